// Round 11
// baseline (1046.017 us; speedup 1.0000x reference)
//
#include <hip/hip_runtime.h>
#include <math.h>

#define NNODES 50000
#define NEDGES 800000

// async global->LDS, 16B per lane; dest = wave-uniform base + lane*16 (linear)
__device__ __forceinline__ void gll16(const float* g, float* l) {
  __builtin_amdgcn_global_load_lds((const __attribute__((address_space(1))) void*)g,
                                   (__attribute__((address_space(3))) void*)l, 16, 0, 0);
}

// ---------------- CSR build ----------------

__global__ void k_zero_int(int* __restrict__ p, int n) {
  int i = blockIdx.x * blockDim.x + threadIdx.x;
  if (i < n) p[i] = 0;
}

__global__ void k_hist(const int* __restrict__ dst, int* __restrict__ deg) {
  int i = blockIdx.x * blockDim.x + threadIdx.x;
  if (i < NEDGES) atomicAdd(&deg[dst[i]], 1);
}

// single-block exclusive scan over NNODES via wave shuffles
__global__ __launch_bounds__(1024) void k_scan(const int* __restrict__ deg,
                                               int* __restrict__ ptr,
                                               int* __restrict__ cur) {
  __shared__ int s_w[16];
  __shared__ int s_carry;
  const int tid = threadIdx.x;
  const int lane = tid & 63;
  const int wid = tid >> 6;
  if (tid == 0) s_carry = 0;
  __syncthreads();
  for (int base = 0; base < NNODES; base += 1024) {
    const int i = base + tid;
    const int v = (i < NNODES) ? deg[i] : 0;
    int x = v;
#pragma unroll
    for (int off = 1; off < 64; off <<= 1) {
      int t = __shfl_up(x, off);
      if (lane >= off) x += t;
    }
    if (lane == 63) s_w[wid] = x;
    __syncthreads();
    const int carry = s_carry;
    if (wid == 0) {
      int ws = (lane < 16) ? s_w[lane] : 0;
#pragma unroll
      for (int off = 1; off < 16; off <<= 1) {
        int t = __shfl_up(ws, off);
        if (lane >= off) ws += t;
      }
      if (lane < 16) s_w[lane] = ws;
    }
    __syncthreads();
    const int woff = (wid > 0) ? s_w[wid - 1] : 0;
    const int excl = carry + woff + (x - v);
    if (i < NNODES) {
      ptr[i] = excl;
      cur[i] = excl;
    }
    __syncthreads();
    if (tid == 0) s_carry = carry + s_w[15];
  }
  __syncthreads();
  if (tid == 0) ptr[NNODES] = s_carry;
}

__global__ void k_scatter(const int* __restrict__ src, const int* __restrict__ dst,
                          int* __restrict__ cur, int* __restrict__ csr) {
  int i = blockIdx.x * blockDim.x + threadIdx.x;
  if (i < NEDGES) {
    int d = dst[i];
    int p = atomicAdd(&cur[d], 1);
    csr[p] = src[i];
  }
}

// ---------------- GEMM + fused el/er epilogue ----------------
// C[M,NC] = A[M,K] @ B[K,NC]. BM=64 x BN tile, 256 threads, 4 x TN acc
// (small acc -> ~75 VGPR, no epilogue spills; 1564 blocks -> 6/CU).
// Double-buffered LDS, ONE barrier per tile. B staged via global_load_lds
// (linear row-major dest); A reg-staged transposed (2-way/free writes).

template <int K, int NC, int BN, int HEADS>
__global__ __launch_bounds__(256, 4) void k_gemm(const float* __restrict__ A,
                                                 const float* __restrict__ B,
                                                 float* __restrict__ C,
                                                 const float* __restrict__ al,
                                                 const float* __restrict__ ar,
                                                 float* __restrict__ el,
                                                 float* __restrict__ er) {
  constexpr int BM = 64;
  constexpr int BK = 16;
  constexpr int TN = BN / 16;
  constexpr int T = K / BK;
  __shared__ float Ast[2][BK][BM + 4];
  __shared__ float Bs[2][BK][BN];
  const int tid = threadIdx.x;
  const int tx = tid & 15;
  const int ty = tid >> 4;
  const int wv = tid >> 6;
  const int l = tid & 63;
  const int rowBase = blockIdx.x * BM;
  const int colBase = blockIdx.y * BN;
  const int arow = tid >> 2;        // 0..63
  const int ak = (tid & 3) << 2;    // 0,4,8,12
  const bool va = (rowBase + arow) < NNODES;
  const float* ap = A + (size_t)(rowBase + arow) * K + ak;
  const float4 z4 = make_float4(0.f, 0.f, 0.f, 0.f);

  // B staging via global_load_lds: wave wv covers rows 4*wv..4*wv+3 per chunk.
  auto stage_B = [&](int k0, int buf) {
    if constexpr (BN == 128) {
      // 2 instrs/wave, each = 2 rows (64 lanes x 16B = 2 x 512B rows)
#pragma unroll
      for (int j = 0; j < 2; ++j) {
        const int row = 4 * wv + 2 * j + (l >> 5);
        gll16(&B[(size_t)(k0 + row) * NC + colBase + ((l & 31) << 2)],
              &Bs[buf][4 * wv + 2 * j][0]);
      }
    } else {
      // BN=64: 1 instr/wave = 4 rows (64 lanes x 16B = 4 x 256B rows)
      const int row = 4 * wv + (l >> 4);
      gll16(&B[(size_t)(k0 + row) * NC + colBase + ((l & 15) << 2)],
            &Bs[buf][4 * wv][0]);
    }
  };

  float4 avr;
  float acc[4][TN] = {};

  // prologue: stage tile 0 into buf 0
  stage_B(0, 0);
  avr = va ? *(const float4*)ap : z4;
  Ast[0][ak + 0][arow] = avr.x;
  Ast[0][ak + 1][arow] = avr.y;
  Ast[0][ak + 2][arow] = avr.z;
  Ast[0][ak + 3][arow] = avr.w;
  __syncthreads();  // compiler drains vmcnt/lgkmcnt here

  for (int t = 0; t < T; ++t) {
    const int cur = t & 1;
    const int nxt = cur ^ 1;
    if (t + 1 < T) {
      stage_B((t + 1) * BK, nxt);
      avr = va ? *(const float4*)(ap + (t + 1) * BK) : z4;
    }
#pragma unroll
    for (int k = 0; k < BK; ++k) {
      float4 fa = *(const float4*)&Ast[cur][k][ty << 2];
      float a[4] = {fa.x, fa.y, fa.z, fa.w};
      float b[TN];
      float4 b0 = *(const float4*)&Bs[cur][k][tx << 2];
      b[0] = b0.x; b[1] = b0.y; b[2] = b0.z; b[3] = b0.w;
      if constexpr (TN == 8) {
        float4 b1 = *(const float4*)&Bs[cur][k][64 + (tx << 2)];
        b[4] = b1.x; b[5] = b1.y; b[6] = b1.z; b[7] = b1.w;
      }
#pragma unroll
      for (int i = 0; i < 4; ++i)
#pragma unroll
        for (int j = 0; j < TN; ++j) acc[i][j] = fmaf(a[i], b[j], acc[i][j]);
    }
    if (t + 1 < T) {
      Ast[nxt][ak + 0][arow] = avr.x;
      Ast[nxt][ak + 1][arow] = avr.y;
      Ast[nxt][ak + 2][arow] = avr.z;
      Ast[nxt][ak + 3][arow] = avr.w;
    }
    __syncthreads();
  }

  // epilogue: C store + fused el/er (each (row, head) owned by one block)
  const int head0 = colBase >> 6;
  float4 alA = *(const float4*)&al[colBase + (tx << 2)];
  float4 arA = *(const float4*)&ar[colBase + (tx << 2)];
  float4 alB = z4, arB = z4;
  if constexpr (TN == 8) {
    alB = *(const float4*)&al[colBase + 64 + (tx << 2)];
    arB = *(const float4*)&ar[colBase + 64 + (tx << 2)];
  }

#pragma unroll
  for (int i = 0; i < 4; ++i) {
    const int r = rowBase + (ty << 2) + i;
    const bool vr = r < NNODES;
    if (vr) {
      float4 o = make_float4(acc[i][0], acc[i][1], acc[i][2], acc[i][3]);
      *(float4*)&C[(size_t)r * NC + colBase + (tx << 2)] = o;
      if constexpr (TN == 8) {
        float4 o2 = make_float4(acc[i][4], acc[i][5], acc[i][6], acc[i][7]);
        *(float4*)&C[(size_t)r * NC + colBase + 64 + (tx << 2)] = o2;
      }
    }
    float pea = acc[i][0] * alA.x + acc[i][1] * alA.y + acc[i][2] * alA.z + acc[i][3] * alA.w;
    float pra = acc[i][0] * arA.x + acc[i][1] * arA.y + acc[i][2] * arA.z + acc[i][3] * arA.w;
    float peb = 0.f, prb = 0.f;
    if constexpr (TN == 8) {
      peb = acc[i][4] * alB.x + acc[i][5] * alB.y + acc[i][6] * alB.z + acc[i][7] * alB.w;
      prb = acc[i][4] * arB.x + acc[i][5] * arB.y + acc[i][6] * arB.z + acc[i][7] * arB.w;
    }
#pragma unroll
    for (int m = 1; m < 16; m <<= 1) {
      pea += __shfl_xor(pea, m);
      pra += __shfl_xor(pra, m);
      if constexpr (TN == 8) {
        peb += __shfl_xor(peb, m);
        prb += __shfl_xor(prb, m);
      }
    }
    if (tx == 0 && vr) {
      el[r * HEADS + head0] = pea;
      er[r * HEADS + head0] = pra;
      if constexpr (TN == 8) {
        el[r * HEADS + head0 + 1] = peb;
        er[r * HEADS + head0 + 1] = prb;
      }
    }
  }
}

// ---------------- per-dst-node softmax + weighted aggregation, single pass ----------

template <int HEADS, bool ACT>
__global__ __launch_bounds__(64) void k_aggregate(const float* __restrict__ h,
                                                  const float* __restrict__ el,
                                                  const float* __restrict__ er,
                                                  const int* __restrict__ ptr,
                                                  const int* __restrict__ csr,
                                                  const float* __restrict__ bias,
                                                  float* __restrict__ out) {
  constexpr int HD = HEADS * 64;
  constexpr int VEC = HEADS;
  constexpr int CH = 64 / HEADS;
  const int n = blockIdx.x;
  const int tid = threadIdx.x;
  const int head = tid / (64 / HEADS);
  const int beg = ptr[n];
  const int deg = ptr[n + 1] - beg;

  __shared__ float s_z[HEADS];
  __shared__ int s_src[CH];
  __shared__ float s_w[64];

  const int hh = tid & (HEADS - 1);
  const int cslot = tid / HEADS;
  const float ern = er[n * HEADS + hh];

  float zacc = 0.f;
  float acc[VEC];
#pragma unroll
  for (int v = 0; v < VEC; ++v) acc[v] = 0.f;

  for (int c0 = 0; c0 < deg; c0 += CH) {
    const int cnt = min(CH, deg - c0);
    __syncthreads();
    if (cslot < cnt) {
      int s = csr[beg + c0 + cslot];
      if (hh == 0) s_src[cslot] = s;
      float e = el[s * HEADS + hh] + ern;
      e = e > 0.f ? e : 0.2f * e;
      float w = expf(e);
      s_w[tid] = w;
      zacc += w;
    }
    __syncthreads();
    for (int c = 0; c < cnt; ++c) {
      const float w = s_w[c * HEADS + head];
      const float* hp = &h[(size_t)s_src[c] * HD + tid * VEC];
      if constexpr (VEC == 4) {
        float4 hv = *(const float4*)hp;
        acc[0] = fmaf(w, hv.x, acc[0]);
        acc[1] = fmaf(w, hv.y, acc[1]);
        acc[2] = fmaf(w, hv.z, acc[2]);
        acc[3] = fmaf(w, hv.w, acc[3]);
      } else {
        acc[0] = fmaf(w, hp[0], acc[0]);
      }
    }
  }

#pragma unroll
  for (int m = HEADS; m < 64; m <<= 1) zacc += __shfl_xor(zacc, m);
  if (tid < HEADS) s_z[tid] = zacc;
  __syncthreads();
  const float invz = (deg > 0) ? 1.0f / s_z[head] : 0.f;

#pragma unroll
  for (int v = 0; v < VEC; ++v) {
    float r = acc[v] * invz + bias[tid * VEC + v];
    if (ACT) r = r > 0.f ? r : expm1f(r);
    acc[v] = r;
  }
  if constexpr (VEC == 4) {
    float4 o = make_float4(acc[0], acc[1], acc[2], acc[3]);
    *(float4*)&out[(size_t)n * HD + (tid << 2)] = o;
  } else {
    out[(size_t)n * HD + tid] = acc[0];
  }
}

// ---------------- launch ----------------

extern "C" void kernel_launch(void* const* d_in, const int* in_sizes, int n_in,
                              void* d_out, int out_size, void* d_ws, size_t ws_size,
                              hipStream_t stream) {
  const float* x   = (const float*)d_in[0];
  const int*   src = (const int*)d_in[1];
  const int*   dst = (const int*)d_in[2];
  const float* W0  = (const float*)d_in[3];
  const float* al0 = (const float*)d_in[4];
  const float* ar0 = (const float*)d_in[5];
  const float* b0  = (const float*)d_in[6];
  const float* W1  = (const float*)d_in[7];
  const float* al1 = (const float*)d_in[8];
  const float* ar1 = (const float*)d_in[9];
  const float* b1  = (const float*)d_in[10];
  const float* W2  = (const float*)d_in[11];
  const float* al2 = (const float*)d_in[12];
  const float* ar2 = (const float*)d_in[13];
  const float* b2  = (const float*)d_in[14];
  float* out = (float*)d_out;

  // workspace carve
  float* hA = (float*)d_ws;                       // N*256
  float* fB = hA + (size_t)NNODES * 256;          // N*256
  float* el = fB + (size_t)NNODES * 256;          // N*4
  float* er = el + (size_t)NNODES * 4;            // N*4
  int* deg  = (int*)(er + (size_t)NNODES * 4);    // N
  int* ptr  = deg + NNODES;                       // N+1
  int* cur  = ptr + NNODES + 1;                   // N
  int* csr  = cur + NNODES;                       // E

  // CSR of incoming edges — built once, reused by all 3 layers
  k_zero_int<<<(NNODES + 255) / 256, 256, 0, stream>>>(deg, NNODES);
  k_hist<<<(NEDGES + 255) / 256, 256, 0, stream>>>(dst, deg);
  k_scan<<<1, 1024, 0, stream>>>(deg, ptr, cur);
  k_scatter<<<(NEDGES + 255) / 256, 256, 0, stream>>>(src, dst, cur, csr);

  dim3 g01((NNODES + 63) / 64, 256 / 128);
  // layer 0: x[N,128] @ W0[128,256] -> hA (+ el/er fused); agg+bias+ELU -> fB
  k_gemm<128, 256, 128, 4><<<g01, 256, 0, stream>>>(x, W0, hA, al0, ar0, el, er);
  k_aggregate<4, true><<<NNODES, 64, 0, stream>>>(hA, el, er, ptr, csr, b0, fB);
  // layer 1
  k_gemm<256, 256, 128, 4><<<g01, 256, 0, stream>>>(fB, W1, hA, al1, ar1, el, er);
  k_aggregate<4, true><<<NNODES, 64, 0, stream>>>(hA, el, er, ptr, csr, b1, fB);
  // layer 2 (mean over 1 head = identity; no activation)
  dim3 g2((NNODES + 63) / 64, 1);
  k_gemm<256, 64, 64, 1><<<g2, 256, 0, stream>>>(fB, W2, hA, al2, ar2, el, er);
  k_aggregate<1, false><<<NNODES, 64, 0, stream>>>(hA, el, er, ptr, csr, b2, out);
}

// Round 12
// 742.983 us; speedup vs baseline: 1.4079x; 1.4079x over previous
//
#include <hip/hip_runtime.h>
#include <math.h>

#define NNODES 50000
#define NEDGES 800000

// ---------------- CSR build ----------------

__global__ void k_zero_int(int* __restrict__ p, int n) {
  int i = blockIdx.x * blockDim.x + threadIdx.x;
  if (i < n) p[i] = 0;
}

__global__ void k_hist(const int* __restrict__ dst, int* __restrict__ deg) {
  int i = blockIdx.x * blockDim.x + threadIdx.x;
  if (i < NEDGES) atomicAdd(&deg[dst[i]], 1);
}

// single-block exclusive scan over NNODES via wave shuffles
__global__ __launch_bounds__(1024) void k_scan(const int* __restrict__ deg,
                                               int* __restrict__ ptr,
                                               int* __restrict__ cur) {
  __shared__ int s_w[16];
  __shared__ int s_carry;
  const int tid = threadIdx.x;
  const int lane = tid & 63;
  const int wid = tid >> 6;
  if (tid == 0) s_carry = 0;
  __syncthreads();
  for (int base = 0; base < NNODES; base += 1024) {
    const int i = base + tid;
    const int v = (i < NNODES) ? deg[i] : 0;
    int x = v;
#pragma unroll
    for (int off = 1; off < 64; off <<= 1) {
      int t = __shfl_up(x, off);
      if (lane >= off) x += t;
    }
    if (lane == 63) s_w[wid] = x;
    __syncthreads();
    const int carry = s_carry;
    if (wid == 0) {
      int ws = (lane < 16) ? s_w[lane] : 0;
#pragma unroll
      for (int off = 1; off < 16; off <<= 1) {
        int t = __shfl_up(ws, off);
        if (lane >= off) ws += t;
      }
      if (lane < 16) s_w[lane] = ws;
    }
    __syncthreads();
    const int woff = (wid > 0) ? s_w[wid - 1] : 0;
    const int excl = carry + woff + (x - v);
    if (i < NNODES) {
      ptr[i] = excl;
      cur[i] = excl;
    }
    __syncthreads();
    if (tid == 0) s_carry = carry + s_w[15];
  }
  __syncthreads();
  if (tid == 0) ptr[NNODES] = s_carry;
}

__global__ void k_scatter(const int* __restrict__ src, const int* __restrict__ dst,
                          int* __restrict__ cur, int* __restrict__ csr) {
  int i = blockIdx.x * blockDim.x + threadIdx.x;
  if (i < NEDGES) {
    int d = dst[i];
    int p = atomicAdd(&cur[d], 1);
    csr[p] = src[i];
  }
}

// ---------------- GEMM + fused el/er epilogue ----------------
// C[M,NC] = A[M,K] @ B[K,NC]. BM=64 x BN tile, 256 threads, 4 x TN acc.
// Round-4 measured-sane staging: global->reg->LDS, single LDS buffer, two
// barriers/tile, next tile prefetched into regs during compute. NO
// global_load_lds (round-11 evidence: 17x HBM write amplification).
// Small acc (32 regs) per round-11 evidence: VGPR=64, no spill.

template <int K, int NC, int BN, int HEADS>
__global__ __launch_bounds__(256) void k_gemm(const float* __restrict__ A,
                                              const float* __restrict__ B,
                                              float* __restrict__ C,
                                              const float* __restrict__ al,
                                              const float* __restrict__ ar,
                                              float* __restrict__ el,
                                              float* __restrict__ er) {
  constexpr int BM = 64;
  constexpr int BK = 16;
  constexpr int TN = BN / 16;
  constexpr int T = K / BK;
  __shared__ float Ast[BK][BM + 4];   // transposed A; 2-way (free) staging aliasing
  __shared__ float Bs[BK][BN];
  const int tid = threadIdx.x;
  const int tx = tid & 15;
  const int ty = tid >> 4;            // 0..15
  const int rowBase = blockIdx.x * BM;
  const int colBase = blockIdx.y * BN;
  const int arow = tid >> 2;          // 0..63
  const int ak = (tid & 3) << 2;      // 0,4,8,12
  const bool va = (rowBase + arow) < NNODES;
  const float* ap = A + (size_t)(rowBase + arow) * K + ak;
  const float4 z4 = make_float4(0.f, 0.f, 0.f, 0.f);

  // B staging indices (regs -> LDS)
  const int brow128 = tid >> 5;          // 0..7   (BN==128: rows brow, brow+8)
  const int bcol128 = (tid & 31) << 2;   // 0..124
  const int brow64 = tid >> 4;           // 0..15  (BN==64)
  const int bcol64 = (tid & 15) << 2;    // 0..60

  float4 avr, bvr0, bvr1;
  auto load_tile = [&](int k0) {
    avr = va ? *(const float4*)(ap + k0) : z4;
    if constexpr (BN == 128) {
      bvr0 = *(const float4*)&B[(size_t)(k0 + brow128) * NC + colBase + bcol128];
      bvr1 = *(const float4*)&B[(size_t)(k0 + brow128 + 8) * NC + colBase + bcol128];
    } else {
      bvr0 = *(const float4*)&B[(size_t)(k0 + brow64) * NC + colBase + bcol64];
    }
  };

  float acc[4][TN] = {};
  load_tile(0);

  for (int t = 0; t < T; ++t) {
    // staged regs -> LDS
    Ast[ak + 0][arow] = avr.x;
    Ast[ak + 1][arow] = avr.y;
    Ast[ak + 2][arow] = avr.z;
    Ast[ak + 3][arow] = avr.w;
    if constexpr (BN == 128) {
      *(float4*)&Bs[brow128][bcol128] = bvr0;
      *(float4*)&Bs[brow128 + 8][bcol128] = bvr1;
    } else {
      *(float4*)&Bs[brow64][bcol64] = bvr0;
    }
    __syncthreads();
    if (t + 1 < T) load_tile((t + 1) * BK);  // HBM latency hides under FMA block
#pragma unroll
    for (int k = 0; k < BK; ++k) {
      float4 fa = *(const float4*)&Ast[k][ty << 2];
      float a[4] = {fa.x, fa.y, fa.z, fa.w};
      float b[TN];
      float4 b0 = *(const float4*)&Bs[k][tx << 2];
      b[0] = b0.x; b[1] = b0.y; b[2] = b0.z; b[3] = b0.w;
      if constexpr (TN == 8) {
        float4 b1 = *(const float4*)&Bs[k][64 + (tx << 2)];
        b[4] = b1.x; b[5] = b1.y; b[6] = b1.z; b[7] = b1.w;
      }
#pragma unroll
      for (int i = 0; i < 4; ++i)
#pragma unroll
        for (int j = 0; j < TN; ++j) acc[i][j] = fmaf(a[i], b[j], acc[i][j]);
    }
    __syncthreads();
  }

  // epilogue: C store + fused el/er (each (row, head) owned by one block)
  const int head0 = colBase >> 6;
  float4 alA = *(const float4*)&al[colBase + (tx << 2)];
  float4 arA = *(const float4*)&ar[colBase + (tx << 2)];
  float4 alB = z4, arB = z4;
  if constexpr (TN == 8) {
    alB = *(const float4*)&al[colBase + 64 + (tx << 2)];
    arB = *(const float4*)&ar[colBase + 64 + (tx << 2)];
  }

#pragma unroll
  for (int i = 0; i < 4; ++i) {
    const int r = rowBase + (ty << 2) + i;
    const bool vr = r < NNODES;
    if (vr) {
      float4 o = make_float4(acc[i][0], acc[i][1], acc[i][2], acc[i][3]);
      *(float4*)&C[(size_t)r * NC + colBase + (tx << 2)] = o;
      if constexpr (TN == 8) {
        float4 o2 = make_float4(acc[i][4], acc[i][5], acc[i][6], acc[i][7]);
        *(float4*)&C[(size_t)r * NC + colBase + 64 + (tx << 2)] = o2;
      }
    }
    float pea = acc[i][0] * alA.x + acc[i][1] * alA.y + acc[i][2] * alA.z + acc[i][3] * alA.w;
    float pra = acc[i][0] * arA.x + acc[i][1] * arA.y + acc[i][2] * arA.z + acc[i][3] * arA.w;
    float peb = 0.f, prb = 0.f;
    if constexpr (TN == 8) {
      peb = acc[i][4] * alB.x + acc[i][5] * alB.y + acc[i][6] * alB.z + acc[i][7] * alB.w;
      prb = acc[i][4] * arB.x + acc[i][5] * arB.y + acc[i][6] * arB.z + acc[i][7] * arB.w;
    }
#pragma unroll
    for (int m = 1; m < 16; m <<= 1) {
      pea += __shfl_xor(pea, m);
      pra += __shfl_xor(pra, m);
      if constexpr (TN == 8) {
        peb += __shfl_xor(peb, m);
        prb += __shfl_xor(prb, m);
      }
    }
    if (tx == 0 && vr) {
      el[r * HEADS + head0] = pea;
      er[r * HEADS + head0] = pra;
      if constexpr (TN == 8) {
        el[r * HEADS + head0 + 1] = peb;
        er[r * HEADS + head0 + 1] = prb;
      }
    }
  }
}

// ---------------- per-dst-node softmax + weighted aggregation, single pass ----------

template <int HEADS, bool ACT>
__global__ __launch_bounds__(64) void k_aggregate(const float* __restrict__ h,
                                                  const float* __restrict__ el,
                                                  const float* __restrict__ er,
                                                  const int* __restrict__ ptr,
                                                  const int* __restrict__ csr,
                                                  const float* __restrict__ bias,
                                                  float* __restrict__ out) {
  constexpr int HD = HEADS * 64;
  constexpr int VEC = HEADS;
  constexpr int CH = 64 / HEADS;
  const int n = blockIdx.x;
  const int tid = threadIdx.x;
  const int head = tid / (64 / HEADS);
  const int beg = ptr[n];
  const int deg = ptr[n + 1] - beg;

  __shared__ float s_z[HEADS];
  __shared__ int s_src[CH];
  __shared__ float s_w[64];

  const int hh = tid & (HEADS - 1);
  const int cslot = tid / HEADS;
  const float ern = er[n * HEADS + hh];

  float zacc = 0.f;
  float acc[VEC];
#pragma unroll
  for (int v = 0; v < VEC; ++v) acc[v] = 0.f;

  for (int c0 = 0; c0 < deg; c0 += CH) {
    const int cnt = min(CH, deg - c0);
    __syncthreads();
    if (cslot < cnt) {
      int s = csr[beg + c0 + cslot];
      if (hh == 0) s_src[cslot] = s;
      float e = el[s * HEADS + hh] + ern;
      e = e > 0.f ? e : 0.2f * e;
      float w = expf(e);
      s_w[tid] = w;
      zacc += w;
    }
    __syncthreads();
    for (int c = 0; c < cnt; ++c) {
      const float w = s_w[c * HEADS + head];
      const float* hp = &h[(size_t)s_src[c] * HD + tid * VEC];
      if constexpr (VEC == 4) {
        float4 hv = *(const float4*)hp;
        acc[0] = fmaf(w, hv.x, acc[0]);
        acc[1] = fmaf(w, hv.y, acc[1]);
        acc[2] = fmaf(w, hv.z, acc[2]);
        acc[3] = fmaf(w, hv.w, acc[3]);
      } else {
        acc[0] = fmaf(w, hp[0], acc[0]);
      }
    }
  }

#pragma unroll
  for (int m = HEADS; m < 64; m <<= 1) zacc += __shfl_xor(zacc, m);
  if (tid < HEADS) s_z[tid] = zacc;
  __syncthreads();
  const float invz = (deg > 0) ? 1.0f / s_z[head] : 0.f;

#pragma unroll
  for (int v = 0; v < VEC; ++v) {
    float r = acc[v] * invz + bias[tid * VEC + v];
    if (ACT) r = r > 0.f ? r : expm1f(r);
    acc[v] = r;
  }
  if constexpr (VEC == 4) {
    float4 o = make_float4(acc[0], acc[1], acc[2], acc[3]);
    *(float4*)&out[(size_t)n * HD + (tid << 2)] = o;
  } else {
    out[(size_t)n * HD + tid] = acc[0];
  }
}

// ---------------- launch ----------------

extern "C" void kernel_launch(void* const* d_in, const int* in_sizes, int n_in,
                              void* d_out, int out_size, void* d_ws, size_t ws_size,
                              hipStream_t stream) {
  const float* x   = (const float*)d_in[0];
  const int*   src = (const int*)d_in[1];
  const int*   dst = (const int*)d_in[2];
  const float* W0  = (const float*)d_in[3];
  const float* al0 = (const float*)d_in[4];
  const float* ar0 = (const float*)d_in[5];
  const float* b0  = (const float*)d_in[6];
  const float* W1  = (const float*)d_in[7];
  const float* al1 = (const float*)d_in[8];
  const float* ar1 = (const float*)d_in[9];
  const float* b1  = (const float*)d_in[10];
  const float* W2  = (const float*)d_in[11];
  const float* al2 = (const float*)d_in[12];
  const float* ar2 = (const float*)d_in[13];
  const float* b2  = (const float*)d_in[14];
  float* out = (float*)d_out;

  // workspace carve
  float* hA = (float*)d_ws;                       // N*256
  float* fB = hA + (size_t)NNODES * 256;          // N*256
  float* el = fB + (size_t)NNODES * 256;          // N*4
  float* er = el + (size_t)NNODES * 4;            // N*4
  int* deg  = (int*)(er + (size_t)NNODES * 4);    // N
  int* ptr  = deg + NNODES;                       // N+1
  int* cur  = ptr + NNODES + 1;                   // N
  int* csr  = cur + NNODES;                       // E

  // CSR of incoming edges — built once, reused by all 3 layers
  k_zero_int<<<(NNODES + 255) / 256, 256, 0, stream>>>(deg, NNODES);
  k_hist<<<(NEDGES + 255) / 256, 256, 0, stream>>>(dst, deg);
  k_scan<<<1, 1024, 0, stream>>>(deg, ptr, cur);
  k_scatter<<<(NEDGES + 255) / 256, 256, 0, stream>>>(src, dst, cur, csr);

  dim3 g01((NNODES + 63) / 64, 256 / 128);
  // layer 0: x[N,128] @ W0[128,256] -> hA (+ el/er fused); agg+bias+ELU -> fB
  k_gemm<128, 256, 128, 4><<<g01, 256, 0, stream>>>(x, W0, hA, al0, ar0, el, er);
  k_aggregate<4, true><<<NNODES, 64, 0, stream>>>(hA, el, er, ptr, csr, b0, fB);
  // layer 1
  k_gemm<256, 256, 128, 4><<<g01, 256, 0, stream>>>(fB, W1, hA, al1, ar1, el, er);
  k_aggregate<4, true><<<NNODES, 64, 0, stream>>>(hA, el, er, ptr, csr, b1, fB);
  // layer 2 (mean over 1 head = identity; no activation)
  dim3 g2((NNODES + 63) / 64, 1);
  k_gemm<256, 64, 64, 1><<<g2, 256, 0, stream>>>(fB, W2, hA, al2, ar2, el, er);
  k_aggregate<1, false><<<NNODES, 64, 0, stream>>>(hA, el, er, ptr, csr, b2, out);
}

// Round 15
// 727.536 us; speedup vs baseline: 1.4378x; 1.0212x over previous
//
#include <hip/hip_runtime.h>
#include <math.h>

#define NNODES 50000
#define NEDGES 800000

// ---------------- CSR build ----------------

__global__ void k_zero_int(int* __restrict__ p, int n) {
  int i = blockIdx.x * blockDim.x + threadIdx.x;
  if (i < n) p[i] = 0;
}

__global__ void k_hist(const int* __restrict__ dst, int* __restrict__ deg) {
  int i = blockIdx.x * blockDim.x + threadIdx.x;
  if (i < NEDGES) atomicAdd(&deg[dst[i]], 1);
}

// single-block exclusive scan over NNODES via wave shuffles
__global__ __launch_bounds__(1024) void k_scan(const int* __restrict__ deg,
                                               int* __restrict__ ptr,
                                               int* __restrict__ cur) {
  __shared__ int s_w[16];
  __shared__ int s_carry;
  const int tid = threadIdx.x;
  const int lane = tid & 63;
  const int wid = tid >> 6;
  if (tid == 0) s_carry = 0;
  __syncthreads();
  for (int base = 0; base < NNODES; base += 1024) {
    const int i = base + tid;
    const int v = (i < NNODES) ? deg[i] : 0;
    int x = v;
#pragma unroll
    for (int off = 1; off < 64; off <<= 1) {
      int t = __shfl_up(x, off);
      if (lane >= off) x += t;
    }
    if (lane == 63) s_w[wid] = x;
    __syncthreads();
    const int carry = s_carry;
    if (wid == 0) {
      int ws = (lane < 16) ? s_w[lane] : 0;
#pragma unroll
      for (int off = 1; off < 16; off <<= 1) {
        int t = __shfl_up(ws, off);
        if (lane >= off) ws += t;
      }
      if (lane < 16) s_w[lane] = ws;
    }
    __syncthreads();
    const int woff = (wid > 0) ? s_w[wid - 1] : 0;
    const int excl = carry + woff + (x - v);
    if (i < NNODES) {
      ptr[i] = excl;
      cur[i] = excl;
    }
    __syncthreads();
    if (tid == 0) s_carry = carry + s_w[15];
  }
  __syncthreads();
  if (tid == 0) ptr[NNODES] = s_carry;
}

__global__ void k_scatter(const int* __restrict__ src, const int* __restrict__ dst,
                          int* __restrict__ cur, int* __restrict__ csr) {
  int i = blockIdx.x * blockDim.x + threadIdx.x;
  if (i < NEDGES) {
    int d = dst[i];
    int p = atomicAdd(&cur[d], 1);
    csr[p] = src[i];
  }
}

// ---------------- GEMM + fused el/er epilogue ----------------
// C[M,NC] = A[M,K] @ B[K,NC]. BM=128 x BN tile, 256 threads, 8 x TN acc.
// Round-12 post-mortem: 4xTN acc was LDS-read-throughput-bound (0.75 B/FLOP,
// VALUBusy 47% ~= model's 44%). 8x8 gives 0.5 B/FLOP; BK=8 keeps staging at
// 2 float4/thread so VGPR ~105 (no round-4 spill). Reg-staged global->reg->LDS,
// single LDS buffer, two barriers/tile, next tile prefetched during compute.

template <int K, int NC, int BN, int HEADS>
__global__ __launch_bounds__(256) void k_gemm(const float* __restrict__ A,
                                              const float* __restrict__ B,
                                              float* __restrict__ C,
                                              const float* __restrict__ al,
                                              const float* __restrict__ ar,
                                              float* __restrict__ el,
                                              float* __restrict__ er) {
  constexpr int BM = 128;
  constexpr int BK = 8;
  constexpr int TN = BN / 16;
  constexpr int T = K / BK;
  __shared__ float Ast[BK][BM + 4];   // transposed A; staging writes 2-way (free)
  __shared__ float Bs[BK][BN];
  const int tid = threadIdx.x;
  const int tx = tid & 15;
  const int ty = tid >> 4;            // 0..15 -> 8 rows each
  const int rowBase = blockIdx.x * BM;
  const int colBase = blockIdx.y * BN;
  const int arow = tid >> 1;          // 0..127
  const int ak = (tid & 1) << 2;      // 0,4
  const bool va = (rowBase + arow) < NNODES;
  const float* ap = A + (size_t)(rowBase + arow) * K + ak;
  const float4 z4 = make_float4(0.f, 0.f, 0.f, 0.f);

  // B staging indices (regs -> LDS)
  const int brow128 = tid >> 5;          // 0..7  (BN==128)
  const int bcol128 = (tid & 31) << 2;
  const int brow64 = tid >> 4;           // 0..15, only tid<128 used (BN==64)
  const int bcol64 = (tid & 15) << 2;

  float4 avr, bvr;
  auto load_tile = [&](int k0) {
    avr = va ? *(const float4*)(ap + k0) : z4;
    if constexpr (BN == 128) {
      bvr = *(const float4*)&B[(size_t)(k0 + brow128) * NC + colBase + bcol128];
    } else {
      if (tid < 128)
        bvr = *(const float4*)&B[(size_t)(k0 + brow64) * NC + colBase + bcol64];
    }
  };

  float acc[8][TN] = {};
  load_tile(0);

  for (int t = 0; t < T; ++t) {
    // staged regs -> LDS
    Ast[ak + 0][arow] = avr.x;
    Ast[ak + 1][arow] = avr.y;
    Ast[ak + 2][arow] = avr.z;
    Ast[ak + 3][arow] = avr.w;
    if constexpr (BN == 128) {
      *(float4*)&Bs[brow128][bcol128] = bvr;
    } else {
      if (tid < 128) *(float4*)&Bs[brow64][bcol64] = bvr;
    }
    __syncthreads();
    if (t + 1 < T) load_tile((t + 1) * BK);  // HBM latency hides under FMA block
#pragma unroll
    for (int k = 0; k < BK; ++k) {
      float4 fa0 = *(const float4*)&Ast[k][ty << 3];
      float4 fa1 = *(const float4*)&Ast[k][(ty << 3) + 4];
      float a[8] = {fa0.x, fa0.y, fa0.z, fa0.w, fa1.x, fa1.y, fa1.z, fa1.w};
      float b[TN];
      float4 b0 = *(const float4*)&Bs[k][tx << 2];
      b[0] = b0.x; b[1] = b0.y; b[2] = b0.z; b[3] = b0.w;
      if constexpr (TN == 8) {
        float4 b1 = *(const float4*)&Bs[k][64 + (tx << 2)];
        b[4] = b1.x; b[5] = b1.y; b[6] = b1.z; b[7] = b1.w;
      }
#pragma unroll
      for (int i = 0; i < 8; ++i)
#pragma unroll
        for (int j = 0; j < TN; ++j) acc[i][j] = fmaf(a[i], b[j], acc[i][j]);
    }
    __syncthreads();
  }

  // epilogue: C store + fused el/er (each (row, head) owned by one block)
  const int head0 = colBase >> 6;
  float4 alA = *(const float4*)&al[colBase + (tx << 2)];
  float4 arA = *(const float4*)&ar[colBase + (tx << 2)];
  float4 alB = z4, arB = z4;
  if constexpr (TN == 8) {
    alB = *(const float4*)&al[colBase + 64 + (tx << 2)];
    arB = *(const float4*)&ar[colBase + 64 + (tx << 2)];
  }

#pragma unroll
  for (int i = 0; i < 8; ++i) {
    const int r = rowBase + (ty << 3) + i;
    const bool vr = r < NNODES;
    if (vr) {
      float4 o = make_float4(acc[i][0], acc[i][1], acc[i][2], acc[i][3]);
      *(float4*)&C[(size_t)r * NC + colBase + (tx << 2)] = o;
      if constexpr (TN == 8) {
        float4 o2 = make_float4(acc[i][4], acc[i][5], acc[i][6], acc[i][7]);
        *(float4*)&C[(size_t)r * NC + colBase + 64 + (tx << 2)] = o2;
      }
    }
    float pea = acc[i][0] * alA.x + acc[i][1] * alA.y + acc[i][2] * alA.z + acc[i][3] * alA.w;
    float pra = acc[i][0] * arA.x + acc[i][1] * arA.y + acc[i][2] * arA.z + acc[i][3] * arA.w;
    float peb = 0.f, prb = 0.f;
    if constexpr (TN == 8) {
      peb = acc[i][4] * alB.x + acc[i][5] * alB.y + acc[i][6] * alB.z + acc[i][7] * alB.w;
      prb = acc[i][4] * arB.x + acc[i][5] * arB.y + acc[i][6] * arB.z + acc[i][7] * arB.w;
    }
#pragma unroll
    for (int m = 1; m < 16; m <<= 1) {
      pea += __shfl_xor(pea, m);
      pra += __shfl_xor(pra, m);
      if constexpr (TN == 8) {
        peb += __shfl_xor(peb, m);
        prb += __shfl_xor(prb, m);
      }
    }
    if (tx == 0 && vr) {
      el[r * HEADS + head0] = pea;
      er[r * HEADS + head0] = pra;
      if constexpr (TN == 8) {
        el[r * HEADS + head0 + 1] = peb;
        er[r * HEADS + head0 + 1] = prb;
      }
    }
  }
}

// ---------------- per-dst-node softmax + weighted aggregation, single pass ----------

template <int HEADS, bool ACT>
__global__ __launch_bounds__(64) void k_aggregate(const float* __restrict__ h,
                                                  const float* __restrict__ el,
                                                  const float* __restrict__ er,
                                                  const int* __restrict__ ptr,
                                                  const int* __restrict__ csr,
                                                  const float* __restrict__ bias,
                                                  float* __restrict__ out) {
  constexpr int HD = HEADS * 64;
  constexpr int VEC = HEADS;
  constexpr int CH = 64 / HEADS;
  const int n = blockIdx.x;
  const int tid = threadIdx.x;
  const int head = tid / (64 / HEADS);
  const int beg = ptr[n];
  const int deg = ptr[n + 1] - beg;

  __shared__ float s_z[HEADS];
  __shared__ int s_src[CH];
  __shared__ float s_w[64];

  const int hh = tid & (HEADS - 1);
  const int cslot = tid / HEADS;
  const float ern = er[n * HEADS + hh];

  float zacc = 0.f;
  float acc[VEC];
#pragma unroll
  for (int v = 0; v < VEC; ++v) acc[v] = 0.f;

  for (int c0 = 0; c0 < deg; c0 += CH) {
    const int cnt = min(CH, deg - c0);
    __syncthreads();
    if (cslot < cnt) {
      int s = csr[beg + c0 + cslot];
      if (hh == 0) s_src[cslot] = s;
      float e = el[s * HEADS + hh] + ern;
      e = e > 0.f ? e : 0.2f * e;
      float w = expf(e);
      s_w[tid] = w;
      zacc += w;
    }
    __syncthreads();
    for (int c = 0; c < cnt; ++c) {
      const float w = s_w[c * HEADS + head];
      const float* hp = &h[(size_t)s_src[c] * HD + tid * VEC];
      if constexpr (VEC == 4) {
        float4 hv = *(const float4*)hp;
        acc[0] = fmaf(w, hv.x, acc[0]);
        acc[1] = fmaf(w, hv.y, acc[1]);
        acc[2] = fmaf(w, hv.z, acc[2]);
        acc[3] = fmaf(w, hv.w, acc[3]);
      } else {
        acc[0] = fmaf(w, hp[0], acc[0]);
      }
    }
  }

#pragma unroll
  for (int m = HEADS; m < 64; m <<= 1) zacc += __shfl_xor(zacc, m);
  if (tid < HEADS) s_z[tid] = zacc;
  __syncthreads();
  const float invz = (deg > 0) ? 1.0f / s_z[head] : 0.f;

#pragma unroll
  for (int v = 0; v < VEC; ++v) {
    float r = acc[v] * invz + bias[tid * VEC + v];
    if (ACT) r = r > 0.f ? r : expm1f(r);
    acc[v] = r;
  }
  if constexpr (VEC == 4) {
    float4 o = make_float4(acc[0], acc[1], acc[2], acc[3]);
    *(float4*)&out[(size_t)n * HD + (tid << 2)] = o;
  } else {
    out[(size_t)n * HD + tid] = acc[0];
  }
}

// ---------------- launch ----------------

extern "C" void kernel_launch(void* const* d_in, const int* in_sizes, int n_in,
                              void* d_out, int out_size, void* d_ws, size_t ws_size,
                              hipStream_t stream) {
  const float* x   = (const float*)d_in[0];
  const int*   src = (const int*)d_in[1];
  const int*   dst = (const int*)d_in[2];
  const float* W0  = (const float*)d_in[3];
  const float* al0 = (const float*)d_in[4];
  const float* ar0 = (const float*)d_in[5];
  const float* b0  = (const float*)d_in[6];
  const float* W1  = (const float*)d_in[7];
  const float* al1 = (const float*)d_in[8];
  const float* ar1 = (const float*)d_in[9];
  const float* b1  = (const float*)d_in[10];
  const float* W2  = (const float*)d_in[11];
  const float* al2 = (const float*)d_in[12];
  const float* ar2 = (const float*)d_in[13];
  const float* b2  = (const float*)d_in[14];
  float* out = (float*)d_out;

  // workspace carve
  float* hA = (float*)d_ws;                       // N*256
  float* fB = hA + (size_t)NNODES * 256;          // N*256
  float* el = fB + (size_t)NNODES * 256;          // N*4
  float* er = el + (size_t)NNODES * 4;            // N*4
  int* deg  = (int*)(er + (size_t)NNODES * 4);    // N
  int* ptr  = deg + NNODES;                       // N+1
  int* cur  = ptr + NNODES + 1;                   // N
  int* csr  = cur + NNODES;                       // E

  // CSR of incoming edges — built once, reused by all 3 layers
  k_zero_int<<<(NNODES + 255) / 256, 256, 0, stream>>>(deg, NNODES);
  k_hist<<<(NEDGES + 255) / 256, 256, 0, stream>>>(dst, deg);
  k_scan<<<1, 1024, 0, stream>>>(deg, ptr, cur);
  k_scatter<<<(NEDGES + 255) / 256, 256, 0, stream>>>(src, dst, cur, csr);

  dim3 g01((NNODES + 127) / 128, 2);
  // layer 0: x[N,128] @ W0[128,256] -> hA (+ el/er fused); agg+bias+ELU -> fB
  k_gemm<128, 256, 128, 4><<<g01, 256, 0, stream>>>(x, W0, hA, al0, ar0, el, er);
  k_aggregate<4, true><<<NNODES, 64, 0, stream>>>(hA, el, er, ptr, csr, b0, fB);
  // layer 1
  k_gemm<256, 256, 128, 4><<<g01, 256, 0, stream>>>(fB, W1, hA, al1, ar1, el, er);
  k_aggregate<4, true><<<NNODES, 64, 0, stream>>>(hA, el, er, ptr, csr, b1, fB);
  // layer 2 (mean over 1 head = identity; no activation)
  dim3 g2((NNODES + 127) / 128, 1);
  k_gemm<256, 64, 64, 1><<<g2, 256, 0, stream>>>(fB, W2, hA, al2, ar2, el, er);
  k_aggregate<1, false><<<NNODES, 64, 0, stream>>>(hA, el, er, ptr, csr, b2, out);
}